// Round 1
// baseline (173.358 us; speedup 1.0000x reference)
//
#include <hip/hip_runtime.h>
#include <math.h>

#define NN 768
#define CC 256
#define TI 3   // rows per block; 768 = 3 * 256 blocks

__device__ __forceinline__ float leaky(float x) { return x >= 0.0f ? x : 0.2f * x; }

__device__ __forceinline__ float waveReduceMax(float v) {
    #pragma unroll
    for (int o = 32; o > 0; o >>= 1) v = fmaxf(v, __shfl_xor(v, o, 64));
    return v;
}
__device__ __forceinline__ float waveReduceSum(float v) {
    #pragma unroll
    for (int o = 32; o > 0; o >>= 1) v += __shfl_xor(v, o, 64);
    return v;
}

// Kernel 1: f_input = features @ FC  -> f [N][C] row-major
//           g[c][j] = fc_w1 * f_input[j][c] + fc_b  -> g [C][N] (transposed, score-ready)
__global__ __launch_bounds__(256) void k_prep(
    const float* __restrict__ features,
    const float* __restrict__ FC,
    const float* __restrict__ fc_w,
    const float* __restrict__ fc_b,
    float* __restrict__ f,
    float* __restrict__ g)
{
    __shared__ float4 sA[CC];   // {feat[i0][k], feat[i0+1][k], feat[i0+2][k], 0}
    const int t  = threadIdx.x;
    const int i0 = blockIdx.x * TI;

    sA[t] = make_float4(features[(i0+0)*CC + t],
                        features[(i0+1)*CC + t],
                        features[(i0+2)*CC + t], 0.0f);
    __syncthreads();

    float a0 = 0.f, a1 = 0.f, a2 = 0.f;
    #pragma unroll 8
    for (int k = 0; k < CC; ++k) {
        float w  = FC[k*CC + t];      // coalesced
        float4 v = sA[k];             // ds_read_b128 broadcast
        a0 = fmaf(v.x, w, a0);
        a1 = fmaf(v.y, w, a1);
        a2 = fmaf(v.z, w, a2);
    }

    const float w1 = fc_w[1], b = fc_b[0];
    f[(i0+0)*CC + t] = a0;
    f[(i0+1)*CC + t] = a1;
    f[(i0+2)*CC + t] = a2;
    g[t*NN + i0+0] = fmaf(w1, a0, b);
    g[t*NN + i0+1] = fmaf(w1, a1, b);
    g[t*NN + i0+2] = fmaf(w1, a2, b);
}

// Kernel 2: fused scores + row-softmax + attention @ f_input + elu.
// One block per TI=3 rows; 256 threads; thread t owns j = t, t+256, t+512.
__global__ __launch_bounds__(256) void k_attn(
    const float* __restrict__ f,      // [N][C]
    const float* __restrict__ g,      // [C][N]
    const float* __restrict__ coords, // [N][3]
    const float* __restrict__ fc_w,
    const float* __restrict__ sc_w,
    const float* __restrict__ sc_b,
    const float* __restrict__ lin_w,  // [C+3]
    const float* __restrict__ lin_b,
    float* __restrict__ out)
{
    __shared__ float4 spack[CC];      // {u_i0[c], u_i1[c], u_i2[c], 0.6*lin_w[c]}
    __shared__ float  swl4[CC];       // 0.4*lin_w[c]
    __shared__ float4 pp[NN];         // {p_i0, p_i1, p_i2, -} per j
    __shared__ float  sredm[4][TI];
    __shared__ float  sreds[4][TI];

    const int t    = threadIdx.x;
    const int i0   = blockIdx.x * TI;
    const int wid  = t >> 6;
    const int lane = t & 63;

    const float w0 = fc_w[0];
    const float wl = lin_w[t];
    spack[t] = make_float4(w0 * f[(i0+0)*CC + t],
                           w0 * f[(i0+1)*CC + t],
                           w0 * f[(i0+2)*CC + t],
                           0.6f * wl);
    swl4[t] = 0.4f * wl;

    const float lw30 = lin_w[CC+0], lw31 = lin_w[CC+1], lw32 = lin_w[CC+2];
    const float sw0 = sc_w[0], sw1 = sc_w[1], sb = sc_b[0], lb = lin_b[0];

    float ax[TI][3];
    #pragma unroll
    for (int r = 0; r < TI; ++r) {
        ax[r][0] = sw0 * coords[(i0+r)*3+0];
        ax[r][1] = sw0 * coords[(i0+r)*3+1];
        ax[r][2] = sw0 * coords[(i0+r)*3+2];
    }
    __syncthreads();

    // ---- Phase 1: scores. leaky(x) = 0.6x + 0.4|x| -> fma + fma(abs mod) ----
    float s[3][TI];
    #pragma unroll
    for (int jj = 0; jj < 3; ++jj)
        #pragma unroll
        for (int r = 0; r < TI; ++r) s[jj][r] = 0.f;

    #pragma unroll 4
    for (int c = 0; c < CC; ++c) {
        float gj[3];
        gj[0] = g[c*NN + t];          // coalesced
        gj[1] = g[c*NN + t + 256];
        gj[2] = g[c*NN + t + 512];
        float4 u  = spack[c];         // b128 broadcast
        float  w4 = swl4[c];
        float ur[3] = {u.x, u.y, u.z};
        #pragma unroll
        for (int jj = 0; jj < 3; ++jj)
            #pragma unroll
            for (int r = 0; r < TI; ++r) {
                float x = ur[r] + gj[jj];
                s[jj][r] = fmaf(u.w, x, fmaf(w4, fabsf(x), s[jj][r]));
            }
    }

    // coordinate part + outer leaky -> final scores in registers
    float scv[3][TI];
    #pragma unroll
    for (int jj = 0; jj < 3; ++jj) {
        int j = t + (jj << 8);
        float c0 = fmaf(sw1, coords[j*3+0], sb);
        float c1 = fmaf(sw1, coords[j*3+1], sb);
        float c2 = fmaf(sw1, coords[j*3+2], sb);
        #pragma unroll
        for (int r = 0; r < TI; ++r) {
            float sd = lw30*leaky(ax[r][0]+c0) + lw31*leaky(ax[r][1]+c1) + lw32*leaky(ax[r][2]+c2);
            scv[jj][r] = leaky(s[jj][r] + sd + lb);
        }
    }

    // ---- Phase 2: row softmax (max, exp, sum) ----
    float m[TI];
    #pragma unroll
    for (int r = 0; r < TI; ++r) {
        m[r] = fmaxf(fmaxf(scv[0][r], scv[1][r]), scv[2][r]);
        float v = waveReduceMax(m[r]);
        if (lane == 0) sredm[wid][r] = v;
    }
    __syncthreads();
    #pragma unroll
    for (int r = 0; r < TI; ++r)
        m[r] = fmaxf(fmaxf(sredm[0][r], sredm[1][r]), fmaxf(sredm[2][r], sredm[3][r]));

    float lsum[TI] = {0.f, 0.f, 0.f};
    #pragma unroll
    for (int jj = 0; jj < 3; ++jj) {
        int j = t + (jj << 8);
        float e0 = __expf(scv[jj][0] - m[0]);
        float e1 = __expf(scv[jj][1] - m[1]);
        float e2 = __expf(scv[jj][2] - m[2]);
        lsum[0] += e0; lsum[1] += e1; lsum[2] += e2;
        pp[j] = make_float4(e0, e1, e2, 0.f);
    }
    #pragma unroll
    for (int r = 0; r < TI; ++r) {
        float v = waveReduceSum(lsum[r]);
        if (lane == 0) sreds[wid][r] = v;
    }
    __syncthreads();
    float inv[TI];
    #pragma unroll
    for (int r = 0; r < TI; ++r)
        inv[r] = 1.0f / (sreds[0][r] + sreds[1][r] + sreds[2][r] + sreds[3][r]);

    // ---- Phase 3: h = P @ f_input (thread t owns channel c=t), then elu ----
    float h[TI] = {0.f, 0.f, 0.f};
    #pragma unroll 4
    for (int j = 0; j < NN; ++j) {
        float fv = f[j*CC + t];       // coalesced
        float4 p = pp[j];             // b128 broadcast
        h[0] = fmaf(p.x, fv, h[0]);
        h[1] = fmaf(p.y, fv, h[1]);
        h[2] = fmaf(p.z, fv, h[2]);
    }
    #pragma unroll
    for (int r = 0; r < TI; ++r) {
        float v = h[r] * inv[r];
        out[(i0+r)*CC + t] = (v > 0.f) ? v : (__expf(v) - 1.0f);
    }
}

extern "C" void kernel_launch(void* const* d_in, const int* in_sizes, int n_in,
                              void* d_out, int out_size, void* d_ws, size_t ws_size,
                              hipStream_t stream) {
    const float* features = (const float*)d_in[0];
    const float* coords   = (const float*)d_in[1];
    // d_in[2] = adj, unused by forward
    const float* FC       = (const float*)d_in[3];
    const float* fc_w     = (const float*)d_in[4];
    const float* fc_b     = (const float*)d_in[5];
    const float* sc_w     = (const float*)d_in[6];
    const float* sc_b     = (const float*)d_in[7];
    const float* lin_w    = (const float*)d_in[8];
    const float* lin_b    = (const float*)d_in[9];
    float* out = (float*)d_out;

    float* f = (float*)d_ws;          // N*C floats
    float* g = f + NN*CC;             // C*N floats  (total 1.5 MiB of ws)

    k_prep<<<NN/TI, 256, 0, stream>>>(features, FC, fc_w, fc_b, f, g);
    k_attn<<<NN/TI, 256, 0, stream>>>(f, g, coords, fc_w, sc_w, sc_b, lin_w, lin_b, out);
}

// Round 2
// 119.744 us; speedup vs baseline: 1.4477x; 1.4477x over previous
//
#include <hip/hip_runtime.h>
#include <math.h>

#define NN 768
#define CC 256
#define TI 3   // rows per block; 768 = 3 * 256 blocks

__device__ __forceinline__ float leaky(float x) { return x >= 0.0f ? x : 0.2f * x; }

__device__ __forceinline__ float waveMax(float v) {
    #pragma unroll
    for (int o = 32; o > 0; o >>= 1) v = fmaxf(v, __shfl_xor(v, o, 64));
    return v;
}
__device__ __forceinline__ float waveSum(float v) {
    #pragma unroll
    for (int o = 32; o > 0; o >>= 1) v += __shfl_xor(v, o, 64);
    return v;
}

// Kernel 1: 256 blocks x 768 threads. Block b owns rows i0..i0+2.
// Thread (r=t>>8, c=t&255) computes f[i0+r][c] = dot(features[i0+r], FC[:,c]).
// Also emits g[c][j] = w1*f[j][c]+b (transposed, score-ready) and per-row
// dot products D0[i]=w0*dot(lin_w,f_i), D1[i]=w1*dot(lin_w,f_i)+fc_b*sum(lin_w).
__global__ __launch_bounds__(768) void k_prep(
    const float* __restrict__ features,
    const float* __restrict__ FC,
    const float* __restrict__ fc_w,
    const float* __restrict__ fc_b,
    const float* __restrict__ lin_w,
    float* __restrict__ f,
    float* __restrict__ g,
    float* __restrict__ D0,
    float* __restrict__ D1)
{
    __shared__ float sA[TI * CC];
    __shared__ float sredD[12], sredW[12];

    const int t  = threadIdx.x;
    const int r  = t >> 8;
    const int c  = t & 255;
    const int i0 = blockIdx.x * TI;

    sA[r * CC + c] = features[(i0 + r) * CC + c];
    __syncthreads();

    float a = 0.f;
    const float* fcp = FC + c;
    const float* ap  = sA + r * CC;
    #pragma unroll 8
    for (int k = 0; k < CC; ++k)
        a = fmaf(ap[k], fcp[k * CC], a);   // LDS broadcast * coalesced global

    const float w1 = fc_w[1], b = fc_b[0];
    f[(i0 + r) * CC + c] = a;
    g[c * NN + i0 + r]   = fmaf(w1, a, b);

    // per-row reductions: D = sum_c lin_w[c]*a ; W = sum_c lin_w[c]
    const float lw = lin_w[c];
    float dv = waveSum(lw * a);
    float wv = waveSum(lw);
    const int wid = t >> 6;
    if ((t & 63) == 0) { sredD[wid] = dv; sredW[wid] = wv; }
    __syncthreads();
    if (t < TI) {
        float D = sredD[t*4] + sredD[t*4+1] + sredD[t*4+2] + sredD[t*4+3];
        float W = sredW[t*4] + sredW[t*4+1] + sredW[t*4+2] + sredW[t*4+3];
        D0[i0 + t] = fc_w[0] * D;
        D1[i0 + t] = fmaf(w1, D, b * W);
    }
}

// Kernel 2: 256 blocks x 768 threads (12 waves). Block owns rows i0..i0+2,
// thread t owns column j=t. Fused scores + softmax + P@f + elu.
__global__ __launch_bounds__(768) void k_attn(
    const float* __restrict__ f,      // [N][C]
    const float* __restrict__ g,      // [C][N]
    const float* __restrict__ D0,     // [N]
    const float* __restrict__ D1,     // [N]
    const float* __restrict__ coords, // [N][3]
    const float* __restrict__ fc_w,
    const float* __restrict__ sc_w,
    const float* __restrict__ sc_b,
    const float* __restrict__ lin_w,  // [C+3]
    const float* __restrict__ lin_b,
    float* __restrict__ out)
{
    __shared__ float4 spack[CC];        // {w0*f_i0[c], w0*f_i1[c], w0*f_i2[c], 0.4*lin_w[c]}
    __shared__ float4 pp[NN];           // exp(score-m) per j for the 3 rows
    __shared__ float  spart[TI][TI][CC];// [q][r][c] phase-3 partials
    __shared__ float  sredm[12][TI];
    __shared__ float  sreds[12][TI];

    const int t    = threadIdx.x;
    const int i0   = blockIdx.x * TI;
    const int wid  = t >> 6;
    const int lane = t & 63;

    const float w0 = fc_w[0];
    if (t < CC) {
        spack[t] = make_float4(w0 * f[(i0+0)*CC + t],
                               w0 * f[(i0+1)*CC + t],
                               w0 * f[(i0+2)*CC + t],
                               0.4f * lin_w[t]);
    }

    const float lw30 = lin_w[CC+0], lw31 = lin_w[CC+1], lw32 = lin_w[CC+2];
    const float sw0 = sc_w[0], sw1 = sc_w[1], sb = sc_b[0], lb = lin_b[0];

    float ax[TI][3];
    #pragma unroll
    for (int r = 0; r < TI; ++r) {
        ax[r][0] = sw0 * coords[(i0+r)*3+0];
        ax[r][1] = sw0 * coords[(i0+r)*3+1];
        ax[r][2] = sw0 * coords[(i0+r)*3+2];
    }
    float bse[TI];
    #pragma unroll
    for (int r = 0; r < TI; ++r) bse[r] = fmaf(0.6f, D0[i0+r], lb);
    const float d1j = D1[t];
    __syncthreads();

    // ---- Phase 1: 0.4*w*|x| accumulation (the 0.6*w*x part is D0/D1) ----
    float s0 = 0.f, s1 = 0.f, s2 = 0.f;
    const float* gp = g + t;
    #pragma unroll 8
    for (int c = 0; c < CC; ++c) {
        float gj = gp[c * NN];          // coalesced, L2-resident
        float4 u = spack[c];            // ds_read_b128 broadcast
        s0 = fmaf(u.w, fabsf(u.x + gj), s0);
        s1 = fmaf(u.w, fabsf(u.y + gj), s1);
        s2 = fmaf(u.w, fabsf(u.z + gj), s2);
    }

    // coordinate part + outer leaky
    float c0 = fmaf(sw1, coords[t*3+0], sb);
    float c1 = fmaf(sw1, coords[t*3+1], sb);
    float c2 = fmaf(sw1, coords[t*3+2], sb);
    float sacc[TI] = {s0, s1, s2};
    float scv[TI];
    #pragma unroll
    for (int r = 0; r < TI; ++r) {
        float sd = lw30*leaky(ax[r][0]+c0) + lw31*leaky(ax[r][1]+c1) + lw32*leaky(ax[r][2]+c2);
        scv[r] = leaky(sacc[r] + sd + fmaf(0.6f, d1j, bse[r]));
    }

    // ---- Phase 2: row softmax over the 768 threads (12 waves) ----
    #pragma unroll
    for (int r = 0; r < TI; ++r) {
        float v = waveMax(scv[r]);
        if (lane == 0) sredm[wid][r] = v;
    }
    __syncthreads();
    float m[TI];
    #pragma unroll
    for (int r = 0; r < TI; ++r) {
        float v = sredm[0][r];
        #pragma unroll
        for (int w = 1; w < 12; ++w) v = fmaxf(v, sredm[w][r]);
        m[r] = v;
    }
    float e0 = __expf(scv[0] - m[0]);
    float e1 = __expf(scv[1] - m[1]);
    float e2 = __expf(scv[2] - m[2]);
    pp[t] = make_float4(e0, e1, e2, 0.f);
    float es[TI] = {e0, e1, e2};
    #pragma unroll
    for (int r = 0; r < TI; ++r) {
        float v = waveSum(es[r]);
        if (lane == 0) sreds[wid][r] = v;
    }
    __syncthreads();
    float inv[TI];
    #pragma unroll
    for (int r = 0; r < TI; ++r) {
        float v = 0.f;
        #pragma unroll
        for (int w = 0; w < 12; ++w) v += sreds[w][r];
        inv[r] = 1.0f / v;
    }

    // ---- Phase 3: h = P @ f. Group q reduces j in [256q, 256q+256). ----
    const int q = t >> 8;
    const int c = t & 255;
    float h0 = 0.f, h1 = 0.f, h2 = 0.f;
    const float* fp = f + (q * 256) * CC + c;
    const float4* pq = pp + q * 256;
    #pragma unroll 8
    for (int jj = 0; jj < 256; ++jj) {
        float fv = fp[jj * CC];         // coalesced
        float4 p = pq[jj];              // b128 broadcast
        h0 = fmaf(p.x, fv, h0);
        h1 = fmaf(p.y, fv, h1);
        h2 = fmaf(p.z, fv, h2);
    }
    spart[q][0][c] = h0;
    spart[q][1][c] = h1;
    spart[q][2][c] = h2;
    __syncthreads();
    if (t < CC) {
        #pragma unroll
        for (int r = 0; r < TI; ++r) {
            float h = spart[0][r][t] + spart[1][r][t] + spart[2][r][t];
            float v = h * inv[r];
            out[(i0 + r) * CC + t] = (v > 0.f) ? v : (__expf(v) - 1.0f);
        }
    }
}

extern "C" void kernel_launch(void* const* d_in, const int* in_sizes, int n_in,
                              void* d_out, int out_size, void* d_ws, size_t ws_size,
                              hipStream_t stream) {
    const float* features = (const float*)d_in[0];
    const float* coords   = (const float*)d_in[1];
    // d_in[2] = adj, unused by forward
    const float* FC       = (const float*)d_in[3];
    const float* fc_w     = (const float*)d_in[4];
    const float* fc_b     = (const float*)d_in[5];
    const float* sc_w     = (const float*)d_in[6];
    const float* sc_b     = (const float*)d_in[7];
    const float* lin_w    = (const float*)d_in[8];
    const float* lin_b    = (const float*)d_in[9];
    float* out = (float*)d_out;

    float* f  = (float*)d_ws;          // N*C
    float* g  = f + NN*CC;             // C*N
    float* D0 = g + CC*NN;             // N
    float* D1 = D0 + NN;               // N   (total ~1.51 MiB of ws)

    k_prep<<<NN/TI, TI*256, 0, stream>>>(features, FC, fc_w, fc_b, lin_w, f, g, D0, D1);
    k_attn<<<NN/TI, TI*256, 0, stream>>>(f, g, D0, D1, coords, fc_w, sc_w, sc_b, lin_w, lin_b, out);
}

// Round 3
// 118.700 us; speedup vs baseline: 1.4605x; 1.0088x over previous
//
#include <hip/hip_runtime.h>
#include <math.h>

#define NN 768
#define CC 256
#define TI 3     // rows per k_prep block
#define RT 12    // rows per k_attn block
#define JC 192   // j columns per k_attn block (3 waves per row-group)
#define NJC 4    // j chunks: 4 * 192 = 768

__device__ __forceinline__ float leaky(float x) { return x >= 0.0f ? x : 0.2f * x; }

__device__ __forceinline__ float waveMax(float v) {
    #pragma unroll
    for (int o = 32; o > 0; o >>= 1) v = fmaxf(v, __shfl_xor(v, o, 64));
    return v;
}
__device__ __forceinline__ float waveSum(float v) {
    #pragma unroll
    for (int o = 32; o > 0; o >>= 1) v += __shfl_xor(v, o, 64);
    return v;
}

// Kernel 1 (unchanged from round 2, ~2 us): f = features @ FC; g = transposed
// score-ready map; D0/D1 = per-row linear-term dot products.
__global__ __launch_bounds__(768) void k_prep(
    const float* __restrict__ features,
    const float* __restrict__ FC,
    const float* __restrict__ fc_w,
    const float* __restrict__ fc_b,
    const float* __restrict__ lin_w,
    float* __restrict__ f,
    float* __restrict__ g,
    float* __restrict__ D0,
    float* __restrict__ D1)
{
    __shared__ float sA[TI * CC];
    __shared__ float sredD[12], sredW[12];

    const int t  = threadIdx.x;
    const int r  = t >> 8;
    const int c  = t & 255;
    const int i0 = blockIdx.x * TI;

    sA[r * CC + c] = features[(i0 + r) * CC + c];
    __syncthreads();

    float a = 0.f;
    const float* fcp = FC + c;
    const float* ap  = sA + r * CC;
    #pragma unroll 8
    for (int k = 0; k < CC; ++k)
        a = fmaf(ap[k], fcp[k * CC], a);

    const float w1 = fc_w[1], b = fc_b[0];
    f[(i0 + r) * CC + c] = a;
    g[c * NN + i0 + r]   = fmaf(w1, a, b);

    const float lw = lin_w[c];
    float dv = waveSum(lw * a);
    float wv = waveSum(lw);
    const int wid = t >> 6;
    if ((t & 63) == 0) { sredD[wid] = dv; sredW[wid] = wv; }
    __syncthreads();
    if (t < TI) {
        float D = sredD[t*4] + sredD[t*4+1] + sredD[t*4+2] + sredD[t*4+3];
        float W = sredW[t*4] + sredW[t*4+1] + sredW[t*4+2] + sredW[t*4+3];
        D0[i0 + t] = fc_w[0] * D;
        D1[i0 + t] = fmaf(w1, D, b * W);
    }
}

// Kernel 2: split-j partial attention. Block = (i-tile of 12 rows) x (j-chunk
// of 192). Emits unnormalized h-partials + per-(row,chunk) softmax stats.
// Thread t: q = t/192 (row-subgroup: rows 3q..3q+2), jj = t%192 (own j).
__global__ __launch_bounds__(768) void k_attn(
    const float* __restrict__ f,      // [N][C]
    const float* __restrict__ g,      // [C][N]
    const float* __restrict__ D0,     // [N]
    const float* __restrict__ D1,     // [N]
    const float* __restrict__ coords, // [N][3]
    const float* __restrict__ fc_w,
    const float* __restrict__ sc_w,
    const float* __restrict__ sc_b,
    const float* __restrict__ lin_w,  // [C+3]
    const float* __restrict__ lin_b,
    float* __restrict__ hp,           // [NJC][N][C] partial sums
    float* __restrict__ Mp,           // [N][NJC] partial max
    float* __restrict__ Lp)           // [N][NJC] partial expsum
{
    __shared__ float4 su4[4 * CC];    // [q][c]: {w0*f_{3q}[c], w0*f_{3q+1}[c], w0*f_{3q+2}[c], 0.4*lin_w[c]}
    __shared__ float  pe[RT * JC];    // [r][jj] unnormalized exp
    __shared__ float  sredm[12][3];
    __shared__ float  sreds[12][3];

    const int t  = threadIdx.x;
    const int it = blockIdx.x >> 2;
    const int jc = blockIdx.x & 3;
    const int i0 = it * RT;
    const int jb = jc * JC;
    const int q  = t / JC;            // 0..3; waves 3q..3q+2
    const int jj = t - q * JC;        // 0..191
    const int j  = jb + jj;
    const int wid  = t >> 6;
    const int lane = t & 63;

    if (t < CC) {
        const float w0  = fc_w[0];
        const float wl4 = 0.4f * lin_w[t];
        #pragma unroll
        for (int qq = 0; qq < 4; ++qq)
            su4[qq * CC + t] = make_float4(w0 * f[(i0 + 3*qq + 0)*CC + t],
                                           w0 * f[(i0 + 3*qq + 1)*CC + t],
                                           w0 * f[(i0 + 3*qq + 2)*CC + t],
                                           wl4);
    }
    __syncthreads();

    // ---- Phase 1: 0.4*w*|x| accumulation over c for own j, 3 rows ----
    float a0 = 0.f, a1 = 0.f, a2 = 0.f;
    const float*  gp  = g + j;
    const float4* sup = su4 + q * CC;
    #pragma unroll 8
    for (int c = 0; c < CC; ++c) {
        float  gj = gp[c * NN];       // coalesced (lanes = consecutive j)
        float4 u  = sup[c];           // ds_read_b128 broadcast
        a0 = fmaf(u.w, fabsf(u.x + gj), a0);
        a1 = fmaf(u.w, fabsf(u.y + gj), a1);
        a2 = fmaf(u.w, fabsf(u.z + gj), a2);
    }

    // coord part + 0.6-linear part + outer leaky
    const float sw0 = sc_w[0], sw1 = sc_w[1], sb = sc_b[0], lb = lin_b[0];
    const float lw30 = lin_w[CC], lw31 = lin_w[CC+1], lw32 = lin_w[CC+2];
    const float cj0 = fmaf(sw1, coords[j*3+0], sb);
    const float cj1 = fmaf(sw1, coords[j*3+1], sb);
    const float cj2 = fmaf(sw1, coords[j*3+2], sb);
    const float d1  = D1[j];
    float accs[3] = {a0, a1, a2};
    float scv[3];
    #pragma unroll
    for (int rr = 0; rr < 3; ++rr) {
        const int i = i0 + 3*q + rr;
        float sd = lw30 * leaky(fmaf(sw0, coords[i*3+0], cj0))
                 + lw31 * leaky(fmaf(sw0, coords[i*3+1], cj1))
                 + lw32 * leaky(fmaf(sw0, coords[i*3+2], cj2));
        scv[rr] = leaky(accs[rr] + sd + 0.6f * (D0[i] + d1) + lb);
    }

    // ---- Phase 2: partial softmax over this block's 192 j's ----
    #pragma unroll
    for (int rr = 0; rr < 3; ++rr) {
        float v = waveMax(scv[rr]);
        if (lane == 0) sredm[wid][rr] = v;
    }
    __syncthreads();
    float m[3];
    #pragma unroll
    for (int rr = 0; rr < 3; ++rr)
        m[rr] = fmaxf(fmaxf(sredm[3*q][rr], sredm[3*q+1][rr]), sredm[3*q+2][rr]);

    float e[3];
    #pragma unroll
    for (int rr = 0; rr < 3; ++rr) {
        e[rr] = __expf(scv[rr] - m[rr]);
        pe[(3*q + rr) * JC + jj] = e[rr];
        float v = waveSum(e[rr]);
        if (lane == 0) sreds[wid][rr] = v;
    }
    __syncthreads();
    if (jj == 0) {
        #pragma unroll
        for (int rr = 0; rr < 3; ++rr) {
            float l = sreds[3*q][rr] + sreds[3*q+1][rr] + sreds[3*q+2][rr];
            Mp[(i0 + 3*q + rr) * NJC + jc] = m[rr];
            Lp[(i0 + 3*q + rr) * NJC + jc] = l;
        }
    }

    // ---- Phase 3: h_part[r][c] = sum_{j in chunk} e_rj * f_j[c] ----
    const int rg = t >> 8;            // 0..2 -> rows 4*rg..4*rg+3
    const int c  = t & 255;
    float h0 = 0.f, h1 = 0.f, h2 = 0.f, h3 = 0.f;
    const float* fp  = f + jb * CC + c;
    const float* pep = pe + (4 * rg) * JC;
    #pragma unroll 4
    for (int jx = 0; jx < JC; ++jx) {
        float fv = fp[jx * CC];       // coalesced; 3x redundancy absorbed by L1
        h0 = fmaf(pep[jx],          fv, h0);
        h1 = fmaf(pep[JC + jx],     fv, h1);
        h2 = fmaf(pep[2*JC + jx],   fv, h2);
        h3 = fmaf(pep[3*JC + jx],   fv, h3);
    }
    float* hpp = hp + ((size_t)jc * NN + i0 + 4*rg) * CC + c;
    hpp[0]      = h0;
    hpp[CC]     = h1;
    hpp[2*CC]   = h2;
    hpp[3*CC]   = h3;
}

// Kernel 3: combine the 4 j-chunk partials per row, normalize, elu.
__global__ __launch_bounds__(256) void k_comb(
    const float* __restrict__ hp,
    const float* __restrict__ Mp,
    const float* __restrict__ Lp,
    float* __restrict__ out)
{
    const int t = threadIdx.x;
    const int i = blockIdx.x;

    float m0 = Mp[i*NJC+0], m1 = Mp[i*NJC+1], m2 = Mp[i*NJC+2], m3 = Mp[i*NJC+3];
    float M  = fmaxf(fmaxf(m0, m1), fmaxf(m2, m3));
    float w0 = __expf(m0 - M), w1 = __expf(m1 - M);
    float w2 = __expf(m2 - M), w3 = __expf(m3 - M);
    float den = w0*Lp[i*NJC+0] + w1*Lp[i*NJC+1] + w2*Lp[i*NJC+2] + w3*Lp[i*NJC+3];
    float inv = 1.0f / den;

    float num = w0 * hp[((size_t)0*NN + i)*CC + t]
              + w1 * hp[((size_t)1*NN + i)*CC + t]
              + w2 * hp[((size_t)2*NN + i)*CC + t]
              + w3 * hp[((size_t)3*NN + i)*CC + t];
    float v = num * inv;
    out[i*CC + t] = (v > 0.f) ? v : (__expf(v) - 1.0f);
}

extern "C" void kernel_launch(void* const* d_in, const int* in_sizes, int n_in,
                              void* d_out, int out_size, void* d_ws, size_t ws_size,
                              hipStream_t stream) {
    const float* features = (const float*)d_in[0];
    const float* coords   = (const float*)d_in[1];
    // d_in[2] = adj, unused by forward
    const float* FC       = (const float*)d_in[3];
    const float* fc_w     = (const float*)d_in[4];
    const float* fc_b     = (const float*)d_in[5];
    const float* sc_w     = (const float*)d_in[6];
    const float* sc_b     = (const float*)d_in[7];
    const float* lin_w    = (const float*)d_in[8];
    const float* lin_b    = (const float*)d_in[9];
    float* out = (float*)d_out;

    float* f  = (float*)d_ws;           // N*C          = 196608
    float* g  = f  + NN*CC;             // C*N          = 196608
    float* D0 = g  + CC*NN;             // N
    float* D1 = D0 + NN;                // N
    float* Mp = D1 + NN;                // N*NJC
    float* Lp = Mp + NN*NJC;            // N*NJC
    float* hp = Lp + NN*NJC;            // NJC*N*C      = 786432 (~4.7 MiB total)

    k_prep<<<NN/TI, 768, 0, stream>>>(features, FC, fc_w, fc_b, lin_w, f, g, D0, D1);
    k_attn<<<(NN/RT)*NJC, 768, 0, stream>>>(f, g, D0, D1, coords, fc_w, sc_w, sc_b,
                                            lin_w, lin_b, hp, Mp, Lp);
    k_comb<<<NN, 256, 0, stream>>>(hp, Mp, Lp, out);
}